// Round 3
// baseline (137.892 us; speedup 1.0000x reference)
//
#include <hip/hip_runtime.h>
#include <cstdint>

#define NAG 25
#define NS 32
#define EHH 3200      // EHH_HID
#define KDIM 800      // N_AGENT*N_S
#define BATCH 2048
#define NEDGE 300
#define NPAD 384      // 300 padded to 3x128
#define KSPLIT 5

typedef _Float16 half8 __attribute__((ext_vector_type(8)));
typedef float f32x4 __attribute__((ext_vector_type(4)));

__device__ __forceinline__ float leaky(float x) { return x >= 0.f ? x : 0.01f * x; }

// ================= K1: stats(50) | cast(800) | W2dT(445) | zero-c(13) =================
// All roles are mutually independent. Batch-norm is folded into K2 via affine identity,
// so the cast role needs no stats -> one serial stage removed vs previous version.
#define STATS_B 50
#define CAST_B  800
#define W2D_B   445
#define ZERO_B  13
__global__ __launch_bounds__(256)
void prep_kernel(const float* __restrict__ states, const float* __restrict__ w1,
                 const float* __restrict__ anova, const int* __restrict__ adj,
                 float* __restrict__ acc, float* __restrict__ cvec,
                 _Float16* __restrict__ A, _Float16* __restrict__ w2dt) {
    __shared__ float redS[32][32];
    __shared__ float redQ[32][32];
    __shared__ int win[EHH];
    const int bi = blockIdx.x;
    const int tid = threadIdx.x;

    if (bi < STATS_B) {
        // ---- partial stats: agent a, batch half hf (1024 rows). No atomics, no init. ----
        const int a = bi >> 1, hf = bi & 1;
        const int s4 = (tid & 7) << 2;
        const int r0 = tid >> 3;
        const float* base = states + ((size_t)a * BATCH + hf * 1024 + r0) * NS + s4;
        f32x4 sum = {0.f, 0.f, 0.f, 0.f};
        f32x4 sq  = {0.f, 0.f, 0.f, 0.f};
#pragma unroll 8
        for (int it = 0; it < 32; ++it) {
            f32x4 v = *(const f32x4*)(base + (size_t)it * 32 * NS);
            sum += v;
            sq  += v * v;
        }
        *(f32x4*)&redS[r0][s4] = sum;
        *(f32x4*)&redQ[r0][s4] = sq;
        __syncthreads();
        if (tid < 32) {
            float s = 0.f, q = 0.f;
#pragma unroll
            for (int r = 0; r < 32; ++r) { s += redS[r][tid]; q += redQ[r][tid]; }
            acc[hf * 800 + a * 32 + tid] = s;          // partial sum
            acc[1600 + hf * 800 + a * 32 + tid] = q;   // partial sumsq
        }
    } else if (bi < STATS_B + CAST_B) {
        // ---- raw cast states f32 -> A fp16 (k-contiguous rows), 8 elems/thread ----
        int u = (bi - STATS_B) * 256 + tid;   // [0, 204800)
        int b = u / 100;
        int fo = (u - b * 100) * 8;
        int a = fo >> 5, s = fo & 31;
        const float* sp = states + ((size_t)a * BATCH + b) * NS + s;
        f32x4 v0 = *(const f32x4*)sp;
        f32x4 v1 = *(const f32x4*)(sp + 4);
        half8 o;
#pragma unroll
        for (int i = 0; i < 4; ++i) o[i] = (_Float16)v0[i];
#pragma unroll
        for (int i = 0; i < 4; ++i) o[4 + i] = (_Float16)v1[i];
        *(half8*)(A + (size_t)b * KDIM + fo) = o;
    } else if (bi < STATS_B + CAST_B + W2D_B) {
        const int bb = bi - (STATS_B + CAST_B);
        if (bb < 313) {
            // ---- per-block LDS edge scatter replay (600 entries, strided) ----
            for (int h = tid; h < EHH; h += 256) win[h] = -1;
            __syncthreads();
            for (int e = tid; e < 2 * NEDGE; e += 256) {
                int pass = e >= NEDGE;
                int ee = pass ? e - NEDGE : e;
                int dest = adj[ee * 4 + (pass ? 3 : 1)];
                atomicMax(&win[dest], e);   // prio = entry index; pass2 > pass1
            }
            __syncthreads();
            // ---- W2dT[a*12+k][h] = att(h,a) * w1[a,h,k] ----
            int t = bb * 256 + tid;   // t = a*3200 + h
            if (t < NAG * EHH) {
                int a = t / EHH;
                int h = t - a * EHH;
                float att = anova[(size_t)h * NAG + a];
                int w = win[h];
                if (w >= 0) {
                    int ee = w >= NEDGE ? w - NEDGE : w;
                    att += anova[(size_t)(EHH + adj[ee * 4]) * NAG + a];
                }
                const float* wp = w1 + ((size_t)a * EHH + h) * 12;
#pragma unroll
                for (int kk = 0; kk < 12; ++kk)
                    w2dt[(size_t)(a * 12 + kk) * EHH + h] = (_Float16)(att * wp[kk]);
            }
        } else {
            // pad rows 300..383 -> zero, 16B per thread
            int p = (bb - 313) * 256 + tid;
            if (p < (NPAD - 300) * EHH / 8) {
                half8 z = {0, 0, 0, 0, 0, 0, 0, 0};
                ((half8*)(w2dt + (size_t)300 * EHH))[p] = z;
            }
        }
    } else {
        int t = (bi - (STATS_B + CAST_B + W2D_B)) * 256 + tid;
        if (t < EHH) cvec[t] = 0.f;
    }
}

// ================= K2: transpose ehh_w with rstd scale + bias accumulation =================
// wt[n][k] = r_k * W[k][n];  cvec[n] += -sum_k mu_k * r_k * W[k][n]
// 625 blocks: 25 k-tiles (32) x 25 n-tiles (128)
__global__ __launch_bounds__(256)
void wscale_kernel(const float* __restrict__ ehh_w, const float* __restrict__ acc,
                   float* __restrict__ cvec, _Float16* __restrict__ wt) {
    __shared__ float tile[32][129];
    __shared__ float mL[32], rL[32];
    __shared__ float cpart[2][128];
    const int bk = blockIdx.x / 25, bn = blockIdx.x % 25;
    const int k0 = bk * 32, n0 = bn * 128;
    const int tid = threadIdx.x;
    if (tid < 32) {
        int f = k0 + tid;
        float s = acc[f] + acc[800 + f];
        float q = acc[1600 + f] + acc[2400 + f];
        float m = s * (1.f / BATCH);
        float var = q * (1.f / BATCH) - m * m;
        mL[tid] = m;
        rL[tid] = rsqrtf(var + 1e-5f);
    }
    __syncthreads();
    const int x = tid & 127, y = tid >> 7;
    float csum = 0.f;
    for (int i = y; i < 32; i += 2) {
        float v = ehh_w[(size_t)(k0 + i) * EHH + n0 + x] * rL[i];
        tile[i][x] = v;
        csum += mL[i] * v;
    }
    cpart[y][x] = csum;
    __syncthreads();
    if (tid < 128) atomicAdd(&cvec[n0 + tid], -(cpart[0][tid] + cpart[1][tid]));
    // write fp16: thread -> (n = tid&127, k-chunk h = tid>>7), 32B per thread
    const int n = tid & 127, h = tid >> 7;
    half8 o0, o1;
#pragma unroll
    for (int j = 0; j < 8; ++j) o0[j] = (_Float16)tile[h * 16 + j][n];
#pragma unroll
    for (int j = 0; j < 8; ++j) o1[j] = (_Float16)tile[h * 16 + 8 + j][n];
    _Float16* wp = wt + (size_t)(n0 + n) * KDIM + k0 + h * 16;
    *(half8*)wp = o0;
    *(half8*)(wp + 8) = o1;
}

// ---------------- 128x128 MFMA GEMM, C = A(MxK) * B^T(NxK), fp16 k-contiguous ----------------
__device__ __forceinline__ void async16(const void* g, void* l) {
    __builtin_amdgcn_global_load_lds(
        (const __attribute__((address_space(1))) void*)(uintptr_t)g,
        (__attribute__((address_space(3))) void*)(unsigned)(uintptr_t)l, 16, 0, 0);
}

template <bool LEAKY_F16_OUT>
__global__ __launch_bounds__(256)
void gemm_bt(const _Float16* __restrict__ A, const _Float16* __restrict__ B,
             _Float16* __restrict__ Ch, float* __restrict__ Cf,
             const float* __restrict__ bias,
             int Ktot, int ldc, int kPerSplit, int slabStride) {
    __shared__ __attribute__((aligned(16))) _Float16 As[2][128 * 32];
    __shared__ __attribute__((aligned(16))) _Float16 Bs[2][128 * 32];
    const int tid = threadIdx.x;
    const int lane = tid & 63;
    const int wave = tid >> 6;            // 4 waves, 2x2
    const int wm = (wave >> 1) << 6;
    const int wn = (wave & 1) << 6;
    const int m0 = blockIdx.x << 7;
    const int n0 = blockIdx.y << 7;
    const int k0 = blockIdx.z * kPerSplit;
    const int nk = kPerSplit >> 5;

    const int srow = lane >> 2;
    const int scol = (lane & 3) << 3;
    const _Float16* gA0 = A + (size_t)(m0 + wave * 16 + srow) * Ktot + k0 + scol;
    const _Float16* gA1 = gA0 + (size_t)64 * Ktot;
    const _Float16* gB0 = B + (size_t)(n0 + wave * 16 + srow) * Ktot + k0 + scol;
    const _Float16* gB1 = gB0 + (size_t)64 * Ktot;
    const int lofs = wave * 512;

    f32x4 acc[4][4];
    const f32x4 zero = {0.f, 0.f, 0.f, 0.f};
#pragma unroll
    for (int i = 0; i < 4; ++i)
#pragma unroll
        for (int j = 0; j < 4; ++j) acc[i][j] = zero;

    const int fr = lane & 15;
    const int q8 = (lane >> 4) << 3;

    async16(gA0, As[0] + lofs);
    async16(gA1, As[0] + 2048 + lofs);
    async16(gB0, Bs[0] + lofs);
    async16(gB1, Bs[0] + 2048 + lofs);

    for (int kt = 0; kt < nk; ++kt) {
        const int cur = kt & 1;
        __syncthreads();
        if (kt + 1 < nk) {
            const int ko = (kt + 1) << 5;
            const int nxt = cur ^ 1;
            async16(gA0 + ko, As[nxt] + lofs);
            async16(gA1 + ko, As[nxt] + 2048 + lofs);
            async16(gB0 + ko, Bs[nxt] + lofs);
            async16(gB1 + ko, Bs[nxt] + 2048 + lofs);
        }
        half8 av[4], bv[4];
#pragma unroll
        for (int i = 0; i < 4; ++i)
            av[i] = *(const half8*)(As[cur] + (wm + i * 16 + fr) * 32 + q8);
#pragma unroll
        for (int j = 0; j < 4; ++j)
            bv[j] = *(const half8*)(Bs[cur] + (wn + j * 16 + fr) * 32 + q8);
#pragma unroll
        for (int i = 0; i < 4; ++i)
#pragma unroll
            for (int j = 0; j < 4; ++j)
                acc[i][j] = __builtin_amdgcn_mfma_f32_16x16x32_f16(av[i], bv[j], acc[i][j], 0, 0, 0);
    }

    // C/D layout: col = lane&15, row = (lane>>4)*4 + reg   [m89-verified]
    const int r0 = (lane >> 4) << 2;
    if (LEAKY_F16_OUT) {
        float cj[4];
#pragma unroll
        for (int j = 0; j < 4; ++j) cj[j] = bias[n0 + wn + j * 16 + fr];
#pragma unroll
        for (int i = 0; i < 4; ++i)
#pragma unroll
            for (int j = 0; j < 4; ++j)
#pragma unroll
                for (int r = 0; r < 4; ++r) {
                    int row = m0 + wm + i * 16 + r0 + r;
                    int col = n0 + wn + j * 16 + fr;
                    Ch[(size_t)row * ldc + col] = (_Float16)leaky(acc[i][j][r] + cj[j]);
                }
    } else {
        float* C = Cf + (size_t)blockIdx.z * slabStride;
#pragma unroll
        for (int i = 0; i < 4; ++i)
#pragma unroll
            for (int j = 0; j < 4; ++j)
#pragma unroll
                for (int r = 0; r < 4; ++r) {
                    int row = m0 + wm + i * 16 + r0 + r;
                    int col = n0 + wn + j * 16 + fr;
                    C[(size_t)row * ldc + col] = acc[i][j][r];
                }
    }
}

// ---------------- tail: reduce split-K, bias+leaky, 12x12, 12x4, action gather ----------------
__global__ void tail_kernel(const float* __restrict__ Hp, const float* __restrict__ b1,
                            const float* __restrict__ w2, const float* __restrict__ b2,
                            const float* __restrict__ w3, const float* __restrict__ b3,
                            const int* __restrict__ act, float* __restrict__ out) {
    int t = blockIdx.x * 256 + threadIdx.x;   // t = a*2048 + b
    int b = t & (BATCH - 1);
    int a = t >> 11;
    const float* hp = Hp + (size_t)b * NPAD + a * 12;
    float h1[12];
#pragma unroll
    for (int k = 0; k < 12; ++k) {
        float s = b1[a * 12 + k];
#pragma unroll
        for (int ks = 0; ks < KSPLIT; ++ks) s += hp[(size_t)ks * BATCH * NPAD + k];
        h1[k] = leaky(s);
    }
    float h2[12];
#pragma unroll
    for (int j = 0; j < 12; ++j) {
        float s = b2[a * 12 + j];
#pragma unroll
        for (int k = 0; k < 12; ++k) s += h1[k] * w2[(a * 12 + k) * 12 + j];
        h2[j] = leaky(s);
    }
    int c = act[t];
    float q = b3[a * 4 + c];
#pragma unroll
    for (int j = 0; j < 12; ++j) q += h2[j] * w3[(a * 12 + j) * 4 + c];
    out[t] = q;
}

extern "C" void kernel_launch(void* const* d_in, const int* in_sizes, int n_in,
                              void* d_out, int out_size, void* d_ws, size_t ws_size,
                              hipStream_t stream) {
    (void)in_sizes; (void)n_in; (void)out_size; (void)ws_size;
    const float* states = (const float*)d_in[0];
    const float* ehh_w  = (const float*)d_in[1];
    const float* anova  = (const float*)d_in[2];
    const float* w1     = (const float*)d_in[3];
    const float* b1     = (const float*)d_in[4];
    const float* w2     = (const float*)d_in[5];
    const float* b2     = (const float*)d_in[6];
    const float* w3     = (const float*)d_in[7];
    const float* b3     = (const float*)d_in[8];
    const int* actions  = (const int*)d_in[9];
    const int* adj      = (const int*)d_in[10];
    float* out = (float*)d_out;

    char* ws = (char*)d_ws;
    float*     acc    = (float*)    (ws + 0);            // 3200 f32 partial stats
    float*     cvec   = (float*)    (ws + 16384);        // 3200 f32 bias
    _Float16*  Abf    = (_Float16*) (ws + 32768);        // 2048*800 fp16
    _Float16*  WbT    = (_Float16*) (ws + 3311616);      // 3200*800 fp16 (scaled)
    _Float16*  W2dT   = (_Float16*) (ws + 8433664);      // 384*3200 fp16
    _Float16*  emb    = (_Float16*) (ws + 10893312);     // 2048*3200 fp16
    float*     Hp     = (float*)    (ws + 24002560);     // KSPLIT*2048*384 f32 (end ~39.7 MB)

    // K1: stats(50) | cast(800) | W2dT(445) | zero-c(13)  -- all independent
    prep_kernel<<<STATS_B + CAST_B + W2D_B + ZERO_B, 256, 0, stream>>>(
        states, w1, anova, adj, acc, cvec, Abf, W2dT);
    // K2: WbT[n][k] = r_k*W[k][n]; cvec[n] -= sum mu_k r_k W[k][n]
    wscale_kernel<<<625, 256, 0, stream>>>(ehh_w, acc, cvec, WbT);
    // K3: emb = leaky(A_raw @ WbT^T + c)   M=2048 N=3200 K=800
    gemm_bt<true><<<dim3(16, 25, 1), 256, 0, stream>>>(Abf, WbT, emb, nullptr, cvec,
                                                       KDIM, EHH, KDIM, 0);
    // K4: Hp = emb @ W2dT^T (split-K x5)   M=2048 N=384 K=3200
    gemm_bt<false><<<dim3(16, 3, KSPLIT), 256, 0, stream>>>(emb, W2dT, nullptr, Hp, nullptr,
                                                            EHH, NPAD, EHH / KSPLIT, BATCH * NPAD);
    // K5: tail
    tail_kernel<<<(BATCH * NAG) / 256, 256, 0, stream>>>(Hp, b1, w2, b2, w3, b3, actions, out);
}

// Round 4
// 133.471 us; speedup vs baseline: 1.0331x; 1.0331x over previous
//
#include <hip/hip_runtime.h>
#include <cstdint>

#define NAG 25
#define NS 32
#define EHH 3200      // EHH_HID
#define KDIM 800      // N_AGENT*N_S
#define BATCH 2048
#define NEDGE 300
#define NPAD 384      // 300 padded to 3x128
#define KSPLIT 5

typedef _Float16 half8 __attribute__((ext_vector_type(8)));
typedef float f32x4 __attribute__((ext_vector_type(4)));

__device__ __forceinline__ float leaky(float x) { return x >= 0.f ? x : 0.01f * x; }

// ================= K1: all order-independent prep (R2-proven) =================
// blocks [0,25): per-agent batch stats -> mean/rstd
// blocks [25,2525): ehh_w transpose 800x3200 f32 -> 3200x800 fp16
// blocks [2525,2970): W2dT build; each block replays edge scatter in LDS
__global__ __launch_bounds__(256)
void prep1_kernel(const float* __restrict__ states, const float* __restrict__ ehh_w,
                  const int* __restrict__ adj, const float* __restrict__ anova,
                  const float* __restrict__ w1,
                  float* __restrict__ mean, float* __restrict__ rstd,
                  _Float16* __restrict__ wt, _Float16* __restrict__ w2dt) {
    __shared__ float redS[32][32];
    __shared__ float redQ[32][32];
    __shared__ float tile[32][33];
    __shared__ int win[EHH];
    const int bi = blockIdx.x;
    const int tid = threadIdx.x;

    if (bi < 25) {
        const int a = bi;
        const int s4 = (tid & 7) << 2;
        const int r0 = tid >> 3;
        const float* base = states + ((size_t)a * BATCH + r0) * NS + s4;
        f32x4 sum = {0.f, 0.f, 0.f, 0.f};
        f32x4 sq  = {0.f, 0.f, 0.f, 0.f};
#pragma unroll 8
        for (int it = 0; it < 64; ++it) {
            f32x4 v = *(const f32x4*)(base + (size_t)it * 32 * NS);
            sum += v;
            sq  += v * v;
        }
        *(f32x4*)&redS[r0][s4] = sum;
        *(f32x4*)&redQ[r0][s4] = sq;
        __syncthreads();
        if (tid < 32) {
            float s = 0.f, q = 0.f;
#pragma unroll
            for (int r = 0; r < 32; ++r) { s += redS[r][tid]; q += redQ[r][tid]; }
            float m = s * (1.f / BATCH);
            float var = q * (1.f / BATCH) - m * m;
            mean[a * 32 + tid] = m;
            rstd[a * 32 + tid] = rsqrtf(var + 1e-5f);
        }
    } else if (bi < 2525) {
        const int bb = bi - 25;
        const int n0 = (bb % 100) * 32, k0 = (bb / 100) * 32;
        const int x = tid & 31, y = tid >> 5;
        for (int i = y; i < 32; i += 8)
            tile[i][x] = ehh_w[(size_t)(k0 + i) * EHH + n0 + x];
        __syncthreads();
        for (int i = y; i < 32; i += 8)
            wt[(size_t)(n0 + i) * KDIM + k0 + x] = (_Float16)tile[x][i];
    } else {
        const int bb = bi - 2525;
        if (bb < 313) {
            for (int h = tid; h < EHH; h += 256) win[h] = -1;
            __syncthreads();
            for (int e = tid; e < 2 * NEDGE; e += 256) {
                int pass = e >= NEDGE;
                int ee = pass ? e - NEDGE : e;
                int dest = adj[ee * 4 + (pass ? 3 : 1)];
                atomicMax(&win[dest], e);   // prio = entry index; pass2 > pass1
            }
            __syncthreads();
            int t = bb * 256 + tid;   // t = a*3200 + h
            if (t < NAG * EHH) {
                int a = t / EHH;
                int h = t - a * EHH;
                float att = anova[(size_t)h * NAG + a];
                int w = win[h];
                if (w >= 0) {
                    int ee = w >= NEDGE ? w - NEDGE : w;
                    att += anova[(size_t)(EHH + adj[ee * 4]) * NAG + a];
                }
                const float* wp = w1 + ((size_t)a * EHH + h) * 12;
#pragma unroll
                for (int kk = 0; kk < 12; ++kk)
                    w2dt[(size_t)(a * 12 + kk) * EHH + h] = (_Float16)(att * wp[kk]);
            }
        } else {
            int p = (bb - 313) * 256 + tid;
            if (p < (NPAD - 300) * EHH / 8) {
                half8 z = {0, 0, 0, 0, 0, 0, 0, 0};
                ((half8*)(w2dt + (size_t)300 * EHH))[p] = z;
            }
        }
    }
}

// ================= K2: normalize -> A fp16, 8 elems/thread (R2-proven) =================
__global__ __launch_bounds__(256)
void norm_kernel(const float* __restrict__ states, const float* __restrict__ mean,
                 const float* __restrict__ rstd, _Float16* __restrict__ A) {
    int u = blockIdx.x * 256 + threadIdx.x;   // [0, 204800)
    int b = u / 100;
    int fo = (u - b * 100) * 8;               // feature offset, multiple of 8
    int a = fo >> 5, s = fo & 31;
    const float* sp = states + ((size_t)a * BATCH + b) * NS + s;
    f32x4 v0 = *(const f32x4*)sp;
    f32x4 v1 = *(const f32x4*)(sp + 4);
    f32x4 m0 = *(const f32x4*)(mean + fo);
    f32x4 m1 = *(const f32x4*)(mean + fo + 4);
    f32x4 r0 = *(const f32x4*)(rstd + fo);
    f32x4 r1 = *(const f32x4*)(rstd + fo + 4);
    half8 out;
#pragma unroll
    for (int i = 0; i < 4; ++i) out[i] = (_Float16)((v0[i] - m0[i]) * r0[i]);
#pragma unroll
    for (int i = 0; i < 4; ++i) out[4 + i] = (_Float16)((v1[i] - m1[i]) * r1[i]);
    *(half8*)(A + (size_t)b * KDIM + fo) = out;
}

// ---------------- MFMA GEMM, C = A(MxK) * B^T(NxK), fp16 k-contiguous ----------------
// Tile = (MI*32) x (NI*32), 4 waves in 2x2. Same double-buffered 1-barrier loop as
// the proven 128x128 version; MI/NI re-tiled for blocks/CU (latency-hiding via
// occupancy: with <2 blocks/CU the per-iter vmcnt(0) drain at __syncthreads is exposed).
__device__ __forceinline__ void async16(const void* g, void* l) {
    __builtin_amdgcn_global_load_lds(
        (const __attribute__((address_space(1))) void*)(uintptr_t)g,
        (__attribute__((address_space(3))) void*)(unsigned)(uintptr_t)l, 16, 0, 0);
}

template <int MI, int NI, bool LEAKY_F16_OUT>
__global__ __launch_bounds__(256)
void gemm_bt(const _Float16* __restrict__ A, const _Float16* __restrict__ B,
             _Float16* __restrict__ Ch, float* __restrict__ Cf,
             int Ktot, int ldc, int kPerSplit, int slabStride) {
    constexpr int BM = MI * 32;
    constexpr int BN = NI * 32;
    __shared__ __attribute__((aligned(16))) _Float16 As[2][BM * 32];
    __shared__ __attribute__((aligned(16))) _Float16 Bs[2][BN * 32];
    const int tid = threadIdx.x;
    const int lane = tid & 63;
    const int wave = tid >> 6;            // 4 waves, 2x2
    const int wm = (wave >> 1) * (MI * 16);
    const int wn = (wave & 1) * (NI * 16);

    // XCD-aware bijective swizzle (nwg % 8 == 0 for both launches)
    const int gx = gridDim.x, gy = gridDim.y;
    int nwg = gx * gy * gridDim.z;
    int bidf = blockIdx.x + gx * (blockIdx.y + gy * blockIdx.z);
    int swz = (bidf & 7) * (nwg >> 3) + (bidf >> 3);
    const int bx = swz % gx;
    const int rem = swz / gx;
    const int by = rem % gy;
    const int bz = rem / gy;

    const int m0 = bx * BM;
    const int n0 = by * BN;
    const int k0 = bz * kPerSplit;
    const int nk = kPerSplit >> 5;

    // staging: each wave covers 16 rows per issue (64 lanes * 16B = 16 rows * 64B)
    const int srow = lane >> 2;
    const int scol = (lane & 3) << 3;
    const _Float16* gA0 = A + (size_t)(m0 + wave * 16 + srow) * Ktot + k0 + scol;
    const _Float16* gA1 = gA0 + (size_t)64 * Ktot;   // used iff BM==128
    const _Float16* gB0 = B + (size_t)(n0 + wave * 16 + srow) * Ktot + k0 + scol;
    const _Float16* gB1 = gB0 + (size_t)64 * Ktot;   // used iff BN==128
    const int lofs = wave * 512;

    f32x4 acc[MI][NI];
    const f32x4 zero = {0.f, 0.f, 0.f, 0.f};
#pragma unroll
    for (int i = 0; i < MI; ++i)
#pragma unroll
        for (int j = 0; j < NI; ++j) acc[i][j] = zero;

    const int fr = lane & 15;
    const int q8 = (lane >> 4) << 3;

    // prologue: stage tile 0 into buffer 0
    async16(gA0, As[0] + lofs);
    if constexpr (BM == 128) async16(gA1, As[0] + 2048 + lofs);
    async16(gB0, Bs[0] + lofs);
    if constexpr (BN == 128) async16(gB1, Bs[0] + 2048 + lofs);

    for (int kt = 0; kt < nk; ++kt) {
        const int cur = kt & 1;
        __syncthreads();   // drains vmcnt(0): buf[cur] staged; readers of buf[cur^1] done
        if (kt + 1 < nk) {
            const int ko = (kt + 1) << 5;
            const int nxt = cur ^ 1;
            async16(gA0 + ko, As[nxt] + lofs);
            if constexpr (BM == 128) async16(gA1 + ko, As[nxt] + 2048 + lofs);
            async16(gB0 + ko, Bs[nxt] + lofs);
            if constexpr (BN == 128) async16(gB1 + ko, Bs[nxt] + 2048 + lofs);
        }
        half8 av[MI], bv[NI];
#pragma unroll
        for (int i = 0; i < MI; ++i)
            av[i] = *(const half8*)(As[cur] + (wm + i * 16 + fr) * 32 + q8);
#pragma unroll
        for (int j = 0; j < NI; ++j)
            bv[j] = *(const half8*)(Bs[cur] + (wn + j * 16 + fr) * 32 + q8);
#pragma unroll
        for (int i = 0; i < MI; ++i)
#pragma unroll
            for (int j = 0; j < NI; ++j)
                acc[i][j] = __builtin_amdgcn_mfma_f32_16x16x32_f16(av[i], bv[j], acc[i][j], 0, 0, 0);
    }

    // C/D layout: col = lane&15, row = (lane>>4)*4 + reg   [m89-verified]
    const int r0 = (lane >> 4) << 2;
    if (LEAKY_F16_OUT) {
#pragma unroll
        for (int i = 0; i < MI; ++i)
#pragma unroll
            for (int j = 0; j < NI; ++j)
#pragma unroll
                for (int r = 0; r < 4; ++r) {
                    int row = m0 + wm + i * 16 + r0 + r;
                    int col = n0 + wn + j * 16 + fr;
                    Ch[(size_t)row * ldc + col] = (_Float16)leaky(acc[i][j][r]);
                }
    } else {
        float* C = Cf + (size_t)bz * slabStride;
#pragma unroll
        for (int i = 0; i < MI; ++i)
#pragma unroll
            for (int j = 0; j < NI; ++j)
#pragma unroll
                for (int r = 0; r < 4; ++r) {
                    int row = m0 + wm + i * 16 + r0 + r;
                    int col = n0 + wn + j * 16 + fr;
                    C[(size_t)row * ldc + col] = acc[i][j][r];
                }
    }
}

// ---------------- tail: reduce split-K, bias+leaky, 12x12, 12x4, action gather ----------------
__global__ void tail_kernel(const float* __restrict__ Hp, const float* __restrict__ b1,
                            const float* __restrict__ w2, const float* __restrict__ b2,
                            const float* __restrict__ w3, const float* __restrict__ b3,
                            const int* __restrict__ act, float* __restrict__ out) {
    int t = blockIdx.x * 256 + threadIdx.x;   // t = a*2048 + b
    int b = t & (BATCH - 1);
    int a = t >> 11;
    const float* hp = Hp + (size_t)b * NPAD + a * 12;
    float h1[12];
#pragma unroll
    for (int k = 0; k < 12; ++k) {
        float s = b1[a * 12 + k];
#pragma unroll
        for (int ks = 0; ks < KSPLIT; ++ks) s += hp[(size_t)ks * BATCH * NPAD + k];
        h1[k] = leaky(s);
    }
    float h2[12];
#pragma unroll
    for (int j = 0; j < 12; ++j) {
        float s = b2[a * 12 + j];
#pragma unroll
        for (int k = 0; k < 12; ++k) s += h1[k] * w2[(a * 12 + k) * 12 + j];
        h2[j] = leaky(s);
    }
    int c = act[t];
    float q = b3[a * 4 + c];
#pragma unroll
    for (int j = 0; j < 12; ++j) q += h2[j] * w3[(a * 12 + j) * 4 + c];
    out[t] = q;
}

extern "C" void kernel_launch(void* const* d_in, const int* in_sizes, int n_in,
                              void* d_out, int out_size, void* d_ws, size_t ws_size,
                              hipStream_t stream) {
    (void)in_sizes; (void)n_in; (void)out_size; (void)ws_size;
    const float* states = (const float*)d_in[0];
    const float* ehh_w  = (const float*)d_in[1];
    const float* anova  = (const float*)d_in[2];
    const float* w1     = (const float*)d_in[3];
    const float* b1     = (const float*)d_in[4];
    const float* w2     = (const float*)d_in[5];
    const float* b2     = (const float*)d_in[6];
    const float* w3     = (const float*)d_in[7];
    const float* b3     = (const float*)d_in[8];
    const int* actions  = (const int*)d_in[9];
    const int* adj      = (const int*)d_in[10];
    float* out = (float*)d_out;

    char* ws = (char*)d_ws;
    float*     mean   = (float*)    (ws + 0);            // 800 f32
    float*     rstd   = (float*)    (ws + 4096);         // 800 f32
    _Float16*  Abf    = (_Float16*) (ws + 32768);        // 2048*800 fp16
    _Float16*  WbT    = (_Float16*) (ws + 3311616);      // 3200*800 fp16
    _Float16*  W2dT   = (_Float16*) (ws + 8433664);      // 384*3200 fp16
    _Float16*  emb    = (_Float16*) (ws + 10893312);     // 2048*3200 fp16
    float*     Hp     = (float*)    (ws + 24002560);     // KSPLIT*2048*384 f32 (end ~39.7 MB)

    // K1: stats(25) | ehh_w transpose(2500) | W2dT build(445)
    prep1_kernel<<<2970, 256, 0, stream>>>(states, ehh_w, adj, anova, w1,
                                           mean, rstd, WbT, W2dT);
    // K2: normalize -> Abf (fp16)
    norm_kernel<<<800, 256, 0, stream>>>(states, mean, rstd, Abf);
    // K3: emb = leaky(A @ WbT^T)   M=2048 N=3200 K=800; 128x64 tiles -> 800 blocks (3.1/CU)
    gemm_bt<4, 2, true><<<dim3(16, 50, 1), 256, 0, stream>>>(Abf, WbT, emb, nullptr,
                                                             KDIM, EHH, KDIM, 0);
    // K4: Hp = emb @ W2dT^T (split-K x5)  M=2048 N=384 K=3200; 64x128 tiles -> 480 blocks
    gemm_bt<2, 4, false><<<dim3(32, 3, KSPLIT), 256, 0, stream>>>(emb, W2dT, nullptr, Hp,
                                                                  EHH, NPAD, EHH / KSPLIT,
                                                                  BATCH * NPAD);
    // K5: tail
    tail_kernel<<<(BATCH * NAG) / 256, 256, 0, stream>>>(Hp, b1, w2, b2, w3, b3, actions, out);
}